// Round 6
// baseline (436.475 us; speedup 1.0000x reference)
//
#include <hip/hip_runtime.h>

// Problem constants (match reference)
#define C 80
#define P 30000
#define G 800
#define BS 256
#define NB 8          // spatial bins per dimension (cell = 128 px, box extent <= 128)
#define NC (NB * NB)  // 64 cells per class
#define NCH 2         // pred z-chunks in match (each block: 2 preds/thread = 512 preds/pass)
#define HCH 8         // hist chunks per class
#define CHSZ ((P + HCH - 1) / HCH)   // 3750
#define P_BLK ((P + BS - 1) / BS)    // 118

// rank order = score desc, then pred-index asc. Packed key is monotone in that
// order (scores >= 0 so float bits are order-preserving). key==0 means "no
// match" (needs score==0.0f AND p==P-1 — probability ~0).
__device__ __forceinline__ unsigned long long pack_key(float s, int p) {
    return ((unsigned long long)__float_as_uint(s) << 32) | (unsigned)(P - 1 - p);
}

// cell of a box by its (x1,y1); boxes span <= 2 cells/dim, so all overlap
// partners of a cell-(bx,by) box lie in the 3x3 cell neighborhood.
__device__ __forceinline__ int cell_of(float x1, float y1) {
    int bx = (int)(x1 * (1.0f / 128.0f));
    int by = (int)(y1 * (1.0f / 128.0f));
    bx = min(max(bx, 0), NB - 1);
    by = min(max(by, 0), NB - 1);
    return by * NB + bx;
}

// ---------------- gt binning: one block per class (count+scan+scatter) ------
// Also zeroes this class's gtKey slice (read-modify by match2 later).
__global__ __launch_bounds__(BS) void gt_bin_kernel(
        const float* __restrict__ gt,
        int* __restrict__ gtCnt, int* __restrict__ gtOff,
        float4* __restrict__ gtBox, float* __restrict__ gtAbe,
        int* __restrict__ gtIdx, unsigned long long* __restrict__ gtKey) {
    __shared__ int h[NC], cur[NC];
    __shared__ int gcell[G];
    const int c = blockIdx.x, tid = threadIdx.x;
    if (tid < NC) h[tid] = 0;
    for (int i = tid; i < G; i += BS) gtKey[c * G + i] = 0ull;
    __syncthreads();
    for (int i = tid; i < G; i += BS) {
        const float* r = gt + ((size_t)c * G + i) * 7;
        int cl = cell_of(r[3], r[4]);
        gcell[i] = cl;
        atomicAdd(&h[cl], 1);
    }
    __syncthreads();
    if (tid < 64) {   // wave 0: exclusive scan over 64 cells
        int v = h[tid], s = v;
        for (int o = 1; o < 64; o <<= 1) { int t = __shfl_up(s, o); if (tid >= o) s += t; }
        int excl = s - v;
        cur[tid] = excl;
        gtOff[c * NC + tid] = excl;
        gtCnt[c * NC + tid] = v;
    }
    __syncthreads();
    for (int i = tid; i < G; i += BS) {
        const float* r = gt + ((size_t)c * G + i) * 7;   // L1-hot (2nd pass)
        float x1 = r[3], y1 = r[4], x2 = r[5], y2 = r[6];
        int slot = atomicAdd(&cur[gcell[i]], 1);
        gtBox[c * G + slot] = make_float4(x1, y1, x2, y2);
        // area + eps pre-folded: cross-compare uses sb = A + (area_g + eps);
        // the -inter terms of the two denominators cancel algebraically.
        gtAbe[c * G + slot] = __fadd_rn(__fmul_rn(__fsub_rn(x2, x1), __fsub_rn(y2, y1)), 1e-9f);
        gtIdx[c * G + slot] = i;
    }
}

// ---------------- pred prep: per-block hist partials (no global atomics) -----
__global__ __launch_bounds__(BS) void pred_prep_kernel(
        const float* __restrict__ pred, int* __restrict__ cntPart,
        float* __restrict__ scoreC, unsigned char* __restrict__ cellB) {
    __shared__ int h[NC];
    const int c = blockIdx.y, blk = blockIdx.x, tid = threadIdx.x;
    if (tid < NC) h[tid] = 0;
    __syncthreads();
    int p = blk * BS + tid;
    if (p < P) {
        const float* r = pred + ((size_t)c * P + p) * 7;
        scoreC[(size_t)c * P + p] = r[2];
        int cl = cell_of(r[3], r[4]);
        cellB[(size_t)c * P + p] = (unsigned char)cl;
        atomicAdd(&h[cl], 1);   // LDS only
    }
    __syncthreads();
    if (tid < NC) cntPart[((size_t)c * P_BLK + blk) * NC + tid] = h[tid];
}

// ---------------- pred scan: sum partials + exclusive scan, 1 block/class ----
// Also zeroes doneCnt (used by fused mean in ap2).
__global__ __launch_bounds__(BS) void pred_scan_kernel(
        const int* __restrict__ cntPart, int* __restrict__ predCnt,
        int* __restrict__ predOff, int* __restrict__ predCur,
        int* __restrict__ doneCnt) {
    __shared__ int acc[4][NC];
    const int c = blockIdx.x, tid = threadIdx.x;
    if (c == 0 && tid == 0) *doneCnt = 0;
    const int cell = tid & 63, grp = tid >> 6;
    int s = 0;
    for (int b = grp; b < P_BLK; b += 4)
        s += cntPart[((size_t)c * P_BLK + b) * NC + cell];
    acc[grp][cell] = s;
    __syncthreads();
    if (tid < 64) {
        int v = acc[0][tid] + acc[1][tid] + acc[2][tid] + acc[3][tid];
        int sc = v;
        for (int o = 1; o < 64; o <<= 1) { int t = __shfl_up(sc, o); if (tid >= o) sc += t; }
        int excl = sc - v;
        predCnt[c * NC + tid] = v;
        predOff[c * NC + tid] = excl;
        predCur[c * NC + tid] = excl;
    }
}

// ---------------- pred scatter: cellB-only read, LDS-aggregated slots -------
__global__ __launch_bounds__(BS) void pred_scatter_kernel(
        const unsigned char* __restrict__ cellB, int* __restrict__ predCur,
        int* __restrict__ predP) {
    __shared__ int h[NC], base[NC];
    const int c = blockIdx.y, tid = threadIdx.x;
    if (tid < NC) h[tid] = 0;
    __syncthreads();
    int p = blockIdx.x * BS + tid;
    int cellv = 0, lr = 0;
    if (p < P) {
        cellv = cellB[(size_t)c * P + p];
        lr = atomicAdd(&h[cellv], 1);   // LDS, local rank
    }
    __syncthreads();
    if (tid < NC && h[tid]) base[tid] = atomicAdd(&predCur[c * NC + tid], h[tid]);
    __syncthreads();
    if (p < P) predP[(size_t)c * P + base[cellv] + lr] = p;
}

// ---------------- match: block per (cell, class, chunk), 2 preds/thread -----
// 3x3 GT neighborhood staged in LDS. Each j-iteration serves TWO preds off one
// sB/sE read: halves LDS+loop overhead per pair, doubles update-chain ILP.
// Argmax via cancelled cross-multiply (iou_g > iou_best <=> in_g*sb_b >
// in_b*sb_g, sb = A + area_g + eps). Epilogue recomputes the reference-order
// denominator exactly, so the >0.5 test uses the bit-exact reference iou.
__global__ __launch_bounds__(BS) void match2_kernel(
        const float* __restrict__ pred,
        const int* __restrict__ gtOff, const int* __restrict__ gtCnt,
        const float4* __restrict__ gtBox, const float* __restrict__ gtAbe,
        const int* __restrict__ gtIdx,
        const int* __restrict__ predOff, const int* __restrict__ predCnt,
        const int* __restrict__ predP,
        unsigned long long* __restrict__ gtKey) {
    __shared__ float4 sB[G];
    __shared__ float  sE[G];
    __shared__ int    sG[G];
    const int c = blockIdx.y, cell = blockIdx.x;
    const int tid = threadIdx.x;

    const int pOff = predOff[c * NC + cell], pCnt = predCnt[c * NC + cell];
    if ((int)(blockIdx.z * (2 * BS)) >= pCnt) return;   // block-uniform exit

    const int cx = cell & (NB - 1), cy = cell >> 3;
    int total = 0;
    for (int dy = -1; dy <= 1; ++dy) {
        int yy = cy + dy; if (yy < 0 || yy >= NB) continue;
        for (int dx = -1; dx <= 1; ++dx) {
            int xx = cx + dx; if (xx < 0 || xx >= NB) continue;
            int nc = yy * NB + xx;
            int off = gtOff[c * NC + nc], cnt = gtCnt[c * NC + nc];
            for (int i = tid; i < cnt; i += BS) {
                sB[total + i] = gtBox[c * G + off + i];
                sE[total + i] = gtAbe[c * G + off + i];
                sG[total + i] = gtIdx[c * G + off + i];
            }
            total += cnt;   // uniform across threads
        }
    }
    __syncthreads();

    const size_t cp = (size_t)c * P;
    for (int i0 = blockIdx.z * (2 * BS) + tid; i0 < pCnt; i0 += NCH * 2 * BS) {
        const int  i1 = i0 + BS;
        const bool a1 = (i1 < pCnt);
        const int  p0 = predP[cp + pOff + i0];
        const int  p1 = predP[cp + pOff + (a1 ? i1 : i0)];
        const float* r0 = pred + (cp + p0) * 7;
        const float* r1 = pred + (cp + p1) * 7;
        float ax0 = r0[3], ay0 = r0[4], bx0 = r0[5], by0 = r0[6];
        float ax1 = r1[3], ay1 = r1[4], bx1 = r1[5], by1 = r1[6];
        float A0 = __fmul_rn(__fsub_rn(bx0, ax0), __fsub_rn(by0, ay0));
        float A1 = __fmul_rn(__fsub_rn(bx1, ax1), __fsub_rn(by1, ay1));
        float IN0 = 0.0f, SB0 = 1.0f; int m0 = -1;
        float IN1 = 0.0f, SB1 = 1.0f; int m1 = -1;
        #pragma unroll 2
        for (int j = 0; j < total; ++j) {
            float4 b = sB[j];
            float  e = sE[j];
            float lx = fmaxf(ax0, b.x), ly = fmaxf(ay0, b.y);
            float rx = fminf(bx0, b.z), ry = fminf(by0, b.w);
            float wx = fmaxf(__fsub_rn(rx, lx), 0.0f);
            float wy = fmaxf(__fsub_rn(ry, ly), 0.0f);
            float in = __fmul_rn(wx, wy);
            float sb = __fadd_rn(A0, e);
            bool  up = __fmul_rn(in, SB0) > __fmul_rn(IN0, sb);
            IN0 = up ? in : IN0; SB0 = up ? sb : SB0; m0 = up ? j : m0;

            lx = fmaxf(ax1, b.x); ly = fmaxf(ay1, b.y);
            rx = fminf(bx1, b.z); ry = fminf(by1, b.w);
            wx = fmaxf(__fsub_rn(rx, lx), 0.0f);
            wy = fmaxf(__fsub_rn(ry, ly), 0.0f);
            in = __fmul_rn(wx, wy);
            sb = __fadd_rn(A1, e);
            up = __fmul_rn(in, SB1) > __fmul_rn(IN1, sb);
            IN1 = up ? in : IN1; SB1 = up ? sb : SB1; m1 = up ? j : m1;
        }
        if (IN0 > 0.0f) {   // zero-inter preds can never be valid
            float4 b = sB[m0];
            float area = __fmul_rn(__fsub_rn(b.z, b.x), __fsub_rn(b.w, b.y));
            float dn = __fadd_rn(__fsub_rn(__fadd_rn(A0, area), IN0), 1e-9f);
            if (__fdiv_rn(IN0, dn) > 0.5f)
                atomicMax(&gtKey[c * G + sG[m0]], pack_key(r0[2], p0));
        }
        if (a1 && IN1 > 0.0f) {
            float4 b = sB[m1];
            float area = __fmul_rn(__fsub_rn(b.z, b.x), __fsub_rn(b.w, b.y));
            float dn = __fadd_rn(__fsub_rn(__fadd_rn(A1, area), IN1), 1e-9f);
            if (__fdiv_rn(IN1, dn) > 0.5f)
                atomicMax(&gtKey[c * G + sG[m1]], pack_key(r1[2], p1));
        }
    }
}

// ---------------- sortc: compact gtKey + position-sort, one block/class -----
// Compaction via LDS atomic; O(T^2) broadcast position-sort (T <= 800, keys
// unique); scatter to a 1024-padded descending array (pad = 0 sorts last).
__global__ __launch_bounds__(BS) void sortc_kernel(
        const unsigned long long* __restrict__ gtKey,
        unsigned long long* __restrict__ sortedKeys, int* __restrict__ sortT) {
    __shared__ unsigned long long k[G];
    __shared__ unsigned long long sk[1024];
    __shared__ int cnt;
    const int c = blockIdx.x, tid = threadIdx.x;
    if (tid == 0) cnt = 0;
    for (int j = tid; j < 1024; j += BS) sk[j] = 0ull;
    __syncthreads();
    for (int i = tid; i < G; i += BS) {
        unsigned long long key = gtKey[c * G + i];
        if (key != 0ull) k[atomicAdd(&cnt, 1)] = key;
    }
    __syncthreads();
    const int T = cnt;
    if (tid == 0) sortT[c] = T;
    for (int t = tid; t < T; t += BS) {
        unsigned long long key = k[t];
        int pos = 0;
        for (int u = 0; u < T; ++u) pos += (k[u] > key) ? 1 : 0;   // keys unique
        sk[pos] = key;
    }
    __syncthreads();
    for (int j = tid; j < 1024; j += BS) sortedKeys[c * 1024 + j] = sk[j];
}

// ---------------- hist: pos(q) for every pred via binary search ----------
// pos(q) = #{TP keys > key_q}; q contributes +1 to rank of every TP at sorted
// position >= pos(q). rank(s) = prefix(hist)[s] - 1 (self-count removed).
// Writes a per-chunk partial histogram (no init, no global atomics).
__global__ __launch_bounds__(BS) void hist_kernel(
        const float* __restrict__ scoreC,
        const unsigned long long* __restrict__ sortedKeys,
        int* __restrict__ gHistPart) {
    __shared__ unsigned long long sK[1024];
    __shared__ int h[1024];
    const int c = blockIdx.y, chunk = blockIdx.x, tid = threadIdx.x;
    for (int j = tid; j < 1024; j += BS) { sK[j] = sortedKeys[c * 1024 + j]; h[j] = 0; }
    __syncthreads();
    const int start = chunk * CHSZ;
    const int end   = min(start + CHSZ, P);
    const float* sc = scoreC + (size_t)c * P;
    for (int i = start + tid; i < end; i += BS) {
        unsigned long long kq =
            ((unsigned long long)__float_as_uint(sc[i]) << 32) | (unsigned)(P - 1 - i);
        int lo = 0;   // count of sorted-desc keys > kq (pads are 0, never > kq)
        #pragma unroll
        for (int step = 512; step > 0; step >>= 1)
            if (sK[lo + step - 1] > kq) lo += step;
        atomicAdd(&h[lo], 1);   // LDS only
    }
    __syncthreads();
    for (int j = tid; j < 1024; j += BS)
        gHistPart[((size_t)c * HCH + chunk) * 1024 + j] = h[j];
}

// ---------------- ap: prefix over hist + closed-form terms + fused mean -----
// TP at sorted position s has ordinal k = s+1 and sorted rank r = prefix-1.
// ctp+cfp == r+1 exactly, so precision = k/(r+1) (1e-9 rounds away in f32);
// term = ((k/800 - (k-1)/800) * (k/(r+1) + (k-1)/r)) * 0.5 — reference op
// order; r == 0 contributes nothing. Last-arriving block computes the mean
// with a deterministic serial in-order sum (same as previous mean_kernel).
__global__ __launch_bounds__(BS) void ap2_kernel(
        const int* __restrict__ sortT, const int* __restrict__ gHistPart,
        float* __restrict__ ap, int* __restrict__ doneCnt,
        float* __restrict__ out) {
    __shared__ int ha[1024];
    __shared__ int hb[1024];
    __shared__ float red[BS];
    __shared__ int lastFlag;
    __shared__ float sap[C];
    const int c = blockIdx.x, tid = threadIdx.x;
    const int T = sortT[c];
    for (int j = tid; j < 1024; j += BS) {
        int v = 0;
        #pragma unroll
        for (int ch = 0; ch < HCH; ++ch)
            v += gHistPart[((size_t)c * HCH + ch) * 1024 + j];
        ha[j] = v;
    }
    __syncthreads();
    int* src = ha; int* dst = hb;
    for (int o = 1; o < 1024; o <<= 1) {
        for (int j = tid; j < 1024; j += BS)
            dst[j] = src[j] + ((j >= o) ? src[j - o] : 0);
        __syncthreads();
        int* tmp = src; src = dst; dst = tmp;
    }
    float sum = 0.0f;
    for (int s = tid; s < T; s += BS) {
        int r = src[s] - 1;          // inclusive prefix minus self
        if (r >= 1) {
            float kf  = (float)(s + 1);
            float km  = (float)s;
            float ri  = __fdiv_rn(kf, 800.0f);
            float rim = __fdiv_rn(km, 800.0f);
            float pi  = __fdiv_rn(kf, (float)(r + 1));
            float pim = __fdiv_rn(km, (float)r);
            sum = __fadd_rn(sum,
                  __fmul_rn(__fmul_rn(__fsub_rn(ri, rim), __fadd_rn(pi, pim)), 0.5f));
        }
    }
    red[tid] = sum;
    __syncthreads();
    for (int s2 = BS / 2; s2 > 0; s2 >>= 1) {
        if (tid < s2) red[tid] = __fadd_rn(red[tid], red[tid + s2]);
        __syncthreads();
    }
    if (tid == 0) {
        ap[c] = red[0];
        __threadfence();                                  // publish ap[c]
        lastFlag = (atomicAdd(doneCnt, 1) == C - 1);      // device-scope
    }
    __syncthreads();
    if (lastFlag) {
        __threadfence();                                  // acquire all ap[]
        if (tid < C) sap[tid] = ((volatile float*)ap)[tid];
        __syncthreads();
        if (tid == 0) {
            float s = 0.0f;
            for (int cc = 0; cc < C; ++cc) s = __fadd_rn(s, sap[cc]);
            out[0] = __fdiv_rn(s, 80.0f);
        }
    }
}

extern "C" void kernel_launch(void* const* d_in, const int* in_sizes, int n_in,
                              void* d_out, int out_size, void* d_ws, size_t ws_size,
                              hipStream_t stream) {
    const float* pred = (const float*)d_in[0];   // [C, P, 7] f32
    const float* gt   = (const float*)d_in[1];   // [C, G, 7] f32
    float* out = (float*)d_out;

    // Workspace layout (~29.5 MB; re-poisoned 0xAA each call — gt_bin /
    // pred_prep / pred_scan / hist fully rewrite everything read-before-write).
    char* ws = (char*)d_ws;
    int*                doneCnt    = (int*)               (ws + 0);
    int*                sortT      = (int*)               (ws + 64);
    float*              ap         = (float*)             (ws + 512);
    int*                predOff    = (int*)               (ws + 1024);     //  20480 B
    int*                predCur    = (int*)               (ws + 21504);
    int*                predCnt    = (int*)               (ws + 41984);
    int*                gtCnt      = (int*)               (ws + 62464);
    int*                gtOff      = (int*)               (ws + 82944);
    int*                gtIdx      = (int*)               (ws + 103424);   // 256000 B
    float*              gtAbe      = (float*)             (ws + 359424);   // 256000 B
    float4*             gtBox      = (float4*)            (ws + 615424);   // 1.024 MB (16-aligned)
    unsigned long long* gtKey      = (unsigned long long*)(ws + 1639424);  // 512000 B
    unsigned long long* sortedKeys = (unsigned long long*)(ws + 2151424);  // 655360 B
    int*                gHistPart  = (int*)               (ws + 2806784);  // 2.62 MB
    int*                cntPart    = (int*)               (ws + 5428224);  // 2.42 MB
    unsigned char*      cellB      = (unsigned char*)     (ws + 7844864);  // 2.4 MB
    int*                predP      = (int*)               (ws + 10244864); // 9.6 MB
    float*              scoreC     = (float*)             (ws + 19844864); // 9.6 MB
    // end: 29444864 B

    gt_bin_kernel<<<C, BS, 0, stream>>>(gt, gtCnt, gtOff, gtBox, gtAbe, gtIdx, gtKey);
    pred_prep_kernel<<<dim3(P_BLK, C), BS, 0, stream>>>(pred, cntPart, scoreC, cellB);
    pred_scan_kernel<<<C, BS, 0, stream>>>(cntPart, predCnt, predOff, predCur, doneCnt);
    pred_scatter_kernel<<<dim3(P_BLK, C), BS, 0, stream>>>(cellB, predCur, predP);
    match2_kernel<<<dim3(NC, C, NCH), BS, 0, stream>>>(pred, gtOff, gtCnt, gtBox, gtAbe, gtIdx,
                                                       predOff, predCnt, predP, gtKey);
    sortc_kernel<<<C, BS, 0, stream>>>(gtKey, sortedKeys, sortT);
    hist_kernel<<<dim3(HCH, C), BS, 0, stream>>>(scoreC, sortedKeys, gHistPart);
    ap2_kernel<<<C, BS, 0, stream>>>(sortT, gHistPart, ap, doneCnt, out);
}

// Round 7
// 396.607 us; speedup vs baseline: 1.1005x; 1.1005x over previous
//
#include <hip/hip_runtime.h>

// Problem constants (match reference)
#define C 80
#define P 30000
#define G 800
#define BS 256
#define NB 8          // spatial bins per dimension (cell = 128 px, box extent <= 128)
#define NC (NB * NB)  // 64 cells per class
#define NCH 3         // pred z-chunks per cell in match
#define HCH 8         // hist chunks per class
#define CHSZ ((P + HCH - 1) / HCH)   // 3750
#define P_BLK ((P + BS - 1) / BS)    // 118

// rank order = score desc, then pred-index asc. Packed key is monotone in that
// order (scores >= 0 so float bits are order-preserving). key==0 means "no
// match" (needs score==0.0f AND p==P-1 — probability ~0).
__device__ __forceinline__ unsigned long long pack_key(float s, int p) {
    return ((unsigned long long)__float_as_uint(s) << 32) | (unsigned)(P - 1 - p);
}

// cell of a box by its (x1,y1); boxes span <= 2 cells/dim, so all overlap
// partners of a cell-(bx,by) box lie in the 3x3 cell neighborhood.
__device__ __forceinline__ int cell_of(float x1, float y1) {
    int bx = (int)(x1 * (1.0f / 128.0f));
    int by = (int)(y1 * (1.0f / 128.0f));
    bx = min(max(bx, 0), NB - 1);
    by = min(max(by, 0), NB - 1);
    return by * NB + bx;
}

// ---------------- gt binning: one block per class (count+scan+scatter) ------
// Also zeroes this class's gtKey / predCnt / gHist slices and doneCnt.
__global__ __launch_bounds__(BS) void gt_bin_kernel(
        const float* __restrict__ gt,
        int* __restrict__ gtCnt, int* __restrict__ gtOff,
        float4* __restrict__ gtBox, float* __restrict__ gtAbe,
        int* __restrict__ gtIdx, unsigned long long* __restrict__ gtKey,
        int* __restrict__ predCnt, int* __restrict__ gHist,
        int* __restrict__ doneCnt) {
    __shared__ int h[NC], cur[NC];
    __shared__ int gcell[G];
    const int c = blockIdx.x, tid = threadIdx.x;
    if (tid < NC) { h[tid] = 0; predCnt[c * NC + tid] = 0; }
    for (int i = tid; i < G; i += BS) gtKey[c * G + i] = 0ull;
    for (int j = tid; j < 1024; j += BS) gHist[c * 1024 + j] = 0;
    if (c == 0 && tid == 0) *doneCnt = 0;
    __syncthreads();
    for (int i = tid; i < G; i += BS) {
        const float* r = gt + ((size_t)c * G + i) * 7;
        int cl = cell_of(r[3], r[4]);
        gcell[i] = cl;
        atomicAdd(&h[cl], 1);
    }
    __syncthreads();
    if (tid < 64) {   // wave 0: exclusive scan over 64 cells
        int v = h[tid], s = v;
        for (int o = 1; o < 64; o <<= 1) { int t = __shfl_up(s, o); if (tid >= o) s += t; }
        int excl = s - v;
        cur[tid] = excl;
        gtOff[c * NC + tid] = excl;
        gtCnt[c * NC + tid] = v;
    }
    __syncthreads();
    for (int i = tid; i < G; i += BS) {
        const float* r = gt + ((size_t)c * G + i) * 7;   // L1-hot (2nd pass)
        float x1 = r[3], y1 = r[4], x2 = r[5], y2 = r[6];
        int slot = atomicAdd(&cur[gcell[i]], 1);
        gtBox[c * G + slot] = make_float4(x1, y1, x2, y2);
        // area + eps pre-folded: cross-compare uses sb = A + (area_g + eps);
        // the -inter terms of the two denominators cancel algebraically.
        gtAbe[c * G + slot] = __fadd_rn(__fmul_rn(__fsub_rn(x2, x1), __fsub_rn(y2, y1)), 1e-9f);
        gtIdx[c * G + slot] = i;
    }
}

// ---------------- pred prep: LDS hist -> one global atomic per (block,cell) --
__global__ __launch_bounds__(BS) void pred_prep_kernel(
        const float* __restrict__ pred, int* __restrict__ predCnt,
        float* __restrict__ scoreC) {
    __shared__ int h[NC];
    const int c = blockIdx.y, tid = threadIdx.x;
    if (tid < NC) h[tid] = 0;
    __syncthreads();
    int p = blockIdx.x * BS + tid;
    if (p < P) {
        const float* r = pred + ((size_t)c * P + p) * 7;
        scoreC[(size_t)c * P + p] = r[2];
        atomicAdd(&h[cell_of(r[3], r[4])], 1);   // LDS
    }
    __syncthreads();
    if (tid < NC && h[tid]) atomicAdd(&predCnt[c * NC + tid], h[tid]);   // no-return
}

// ---------------- pred scan: one wave per class ----------------
__global__ void pred_scan_kernel(const int* __restrict__ predCnt,
                                 int* __restrict__ predOff, int* __restrict__ predCur) {
    const int c = blockIdx.x, lane = threadIdx.x;   // block = 64
    int v = predCnt[c * NC + lane], s = v;
    for (int o = 1; o < 64; o <<= 1) { int t = __shfl_up(s, o); if (lane >= o) s += t; }
    int excl = s - v;
    predOff[c * NC + lane] = excl;
    predCur[c * NC + lane] = excl;
}

// ---------------- pred scatter (staged): write cell-sorted box + pid --------
// LDS local-rank + one global return-atomic per (block,cell); writes the
// box itself in cell order so match2 reads coalesced float4 (fixes the 2.2x
// line overfetch + latency bursts of predP-indirected 28-B row reads).
__global__ __launch_bounds__(BS) void pred_scatter_staged_kernel(
        const float* __restrict__ pred, int* __restrict__ predCur,
        float4* __restrict__ sBox, unsigned short* __restrict__ sPid) {
    __shared__ int h[NC], base[NC];
    const int c = blockIdx.y, tid = threadIdx.x;
    if (tid < NC) h[tid] = 0;
    __syncthreads();
    int p = blockIdx.x * BS + tid;
    float4 box = make_float4(0.f, 0.f, 0.f, 0.f);
    int cellv = 0, lr = 0;
    if (p < P) {
        const float* r = pred + ((size_t)c * P + p) * 7;
        box = make_float4(r[3], r[4], r[5], r[6]);
        cellv = cell_of(box.x, box.y);
        lr = atomicAdd(&h[cellv], 1);   // LDS, local rank
    }
    __syncthreads();
    if (tid < NC && h[tid]) base[tid] = atomicAdd(&predCur[c * NC + tid], h[tid]);
    __syncthreads();
    if (p < P) {
        int slot = base[cellv] + lr;
        sBox[(size_t)c * P + slot] = box;
        sPid[(size_t)c * P + slot] = (unsigned short)p;
    }
}

// ---------------- pred scatter (fallback): index only ----------------
__global__ __launch_bounds__(BS) void pred_scatter_direct_kernel(
        const float* __restrict__ pred, int* __restrict__ predCur,
        int* __restrict__ predP) {
    __shared__ int h[NC], base[NC];
    const int c = blockIdx.y, tid = threadIdx.x;
    if (tid < NC) h[tid] = 0;
    __syncthreads();
    int p = blockIdx.x * BS + tid;
    int cellv = 0, lr = 0;
    if (p < P) {
        const float* r = pred + ((size_t)c * P + p) * 7;
        cellv = cell_of(r[3], r[4]);
        lr = atomicAdd(&h[cellv], 1);
    }
    __syncthreads();
    if (tid < NC && h[tid]) base[tid] = atomicAdd(&predCur[c * NC + tid], h[tid]);
    __syncthreads();
    if (p < P) predP[(size_t)c * P + base[cellv] + lr] = p;
}

// ---------------- match (staged): block per (cell, class, chunk) ------------
// 3x3 GT neighborhood staged in LDS; pred boxes read as coalesced float4 from
// the cell-sorted staging array. Argmax via cancelled cross-multiply
// (iou_g > iou_best <=> in_g*sb_b > in_b*sb_g, sb = A + area_g + eps).
// Epilogue recomputes the reference-order denominator exactly, so the >0.5
// test uses the bit-exact reference iou.
__global__ __launch_bounds__(BS) void match_staged_kernel(
        const int* __restrict__ gtOff, const int* __restrict__ gtCnt,
        const float4* __restrict__ gtBox, const float* __restrict__ gtAbe,
        const int* __restrict__ gtIdx,
        const int* __restrict__ predOff, const int* __restrict__ predCnt,
        const float4* __restrict__ sBox, const unsigned short* __restrict__ sPid,
        const float* __restrict__ scoreC,
        unsigned long long* __restrict__ gtKey) {
    __shared__ float4 sB[G];
    __shared__ float  sE[G];
    __shared__ int    sG[G];
    const int c = blockIdx.y, cell = blockIdx.x;
    const int tid = threadIdx.x;

    const int pOff = predOff[c * NC + cell], pCnt = predCnt[c * NC + cell];
    if ((int)(blockIdx.z * BS) >= pCnt) return;   // block-uniform early exit

    const int cx = cell & (NB - 1), cy = cell >> 3;
    int total = 0;
    for (int dy = -1; dy <= 1; ++dy) {
        int yy = cy + dy; if (yy < 0 || yy >= NB) continue;
        for (int dx = -1; dx <= 1; ++dx) {
            int xx = cx + dx; if (xx < 0 || xx >= NB) continue;
            int nc = yy * NB + xx;
            int off = gtOff[c * NC + nc], cnt = gtCnt[c * NC + nc];
            for (int i = tid; i < cnt; i += BS) {
                sB[total + i] = gtBox[c * G + off + i];
                sE[total + i] = gtAbe[c * G + off + i];
                sG[total + i] = gtIdx[c * G + off + i];
            }
            total += cnt;   // uniform across threads
        }
    }
    __syncthreads();

    const size_t cp = (size_t)c * P;
    for (int i = blockIdx.z * BS + tid; i < pCnt; i += NCH * BS) {
        float4 pb = sBox[cp + pOff + i];           // coalesced float4
        float ax1 = pb.x, ay1 = pb.y, ax2 = pb.z, ay2 = pb.w;
        float A   = __fmul_rn(__fsub_rn(ax2, ax1), __fsub_rn(ay2, ay1));
        float IN = 0.0f, SB = 1.0f;
        int mj = -1;
        #pragma unroll 4
        for (int j = 0; j < total; ++j) {
            float4 b = sB[j];
            float lx = fmaxf(ax1, b.x), ly = fmaxf(ay1, b.y);
            float rx = fminf(ax2, b.z), ry = fminf(ay2, b.w);
            float wx = fmaxf(__fsub_rn(rx, lx), 0.0f);
            float wy = fmaxf(__fsub_rn(ry, ly), 0.0f);
            float in = __fmul_rn(wx, wy);
            float sb = __fadd_rn(A, sE[j]);
            bool  up = __fmul_rn(in, SB) > __fmul_rn(IN, sb);
            IN = up ? in : IN; SB = up ? sb : SB; mj = up ? j : mj;
        }
        if (IN > 0.0f) {   // zero-inter preds can never be valid
            float4 b = sB[mj];
            float area = __fmul_rn(__fsub_rn(b.z, b.x), __fsub_rn(b.w, b.y));
            float dn = __fadd_rn(__fsub_rn(__fadd_rn(A, area), IN), 1e-9f);
            if (__fdiv_rn(IN, dn) > 0.5f) {        // exact reference iou
                int p = (int)sPid[cp + pOff + i];
                float s = scoreC[cp + p];          // rare path
                atomicMax(&gtKey[c * G + sG[mj]], pack_key(s, p));
            }
        }
    }
}

// ---------------- match (fallback): R5 form, predP-indirected rows ----------
__global__ __launch_bounds__(BS) void match_direct_kernel(
        const float* __restrict__ pred,
        const int* __restrict__ gtOff, const int* __restrict__ gtCnt,
        const float4* __restrict__ gtBox, const float* __restrict__ gtAbe,
        const int* __restrict__ gtIdx,
        const int* __restrict__ predOff, const int* __restrict__ predCnt,
        const int* __restrict__ predP,
        unsigned long long* __restrict__ gtKey) {
    __shared__ float4 sB[G];
    __shared__ float  sE[G];
    __shared__ int    sG[G];
    const int c = blockIdx.y, cell = blockIdx.x;
    const int tid = threadIdx.x;

    const int pOff = predOff[c * NC + cell], pCnt = predCnt[c * NC + cell];
    if ((int)(blockIdx.z * BS) >= pCnt) return;

    const int cx = cell & (NB - 1), cy = cell >> 3;
    int total = 0;
    for (int dy = -1; dy <= 1; ++dy) {
        int yy = cy + dy; if (yy < 0 || yy >= NB) continue;
        for (int dx = -1; dx <= 1; ++dx) {
            int xx = cx + dx; if (xx < 0 || xx >= NB) continue;
            int nc = yy * NB + xx;
            int off = gtOff[c * NC + nc], cnt = gtCnt[c * NC + nc];
            for (int i = tid; i < cnt; i += BS) {
                sB[total + i] = gtBox[c * G + off + i];
                sE[total + i] = gtAbe[c * G + off + i];
                sG[total + i] = gtIdx[c * G + off + i];
            }
            total += cnt;
        }
    }
    __syncthreads();

    for (int i = blockIdx.z * BS + tid; i < pCnt; i += NCH * BS) {
        int p = predP[(size_t)c * P + pOff + i];
        const float* r = pred + ((size_t)c * P + p) * 7;
        float ax1 = r[3], ay1 = r[4], ax2 = r[5], ay2 = r[6];
        float A   = __fmul_rn(__fsub_rn(ax2, ax1), __fsub_rn(ay2, ay1));
        float IN = 0.0f, SB = 1.0f;
        int mj = -1;
        #pragma unroll 4
        for (int j = 0; j < total; ++j) {
            float4 b = sB[j];
            float lx = fmaxf(ax1, b.x), ly = fmaxf(ay1, b.y);
            float rx = fminf(ax2, b.z), ry = fminf(ay2, b.w);
            float wx = fmaxf(__fsub_rn(rx, lx), 0.0f);
            float wy = fmaxf(__fsub_rn(ry, ly), 0.0f);
            float in = __fmul_rn(wx, wy);
            float sb = __fadd_rn(A, sE[j]);
            bool  up = __fmul_rn(in, SB) > __fmul_rn(IN, sb);
            IN = up ? in : IN; SB = up ? sb : SB; mj = up ? j : mj;
        }
        if (IN > 0.0f) {
            float4 b = sB[mj];
            float area = __fmul_rn(__fsub_rn(b.z, b.x), __fsub_rn(b.w, b.y));
            float dn = __fadd_rn(__fsub_rn(__fadd_rn(A, area), IN), 1e-9f);
            if (__fdiv_rn(IN, dn) > 0.5f) {
                float s = r[2];
                atomicMax(&gtKey[c * G + sG[mj]], pack_key(s, p));
            }
        }
    }
}

// ---------------- sortc: compact gtKey + position-sort, one block/class -----
__global__ __launch_bounds__(BS) void sortc_kernel(
        const unsigned long long* __restrict__ gtKey,
        unsigned long long* __restrict__ sortedKeys, int* __restrict__ sortT) {
    __shared__ unsigned long long k[G];
    __shared__ unsigned long long sk[1024];
    __shared__ int cnt;
    const int c = blockIdx.x, tid = threadIdx.x;
    if (tid == 0) cnt = 0;
    for (int j = tid; j < 1024; j += BS) sk[j] = 0ull;
    __syncthreads();
    for (int i = tid; i < G; i += BS) {
        unsigned long long key = gtKey[c * G + i];
        if (key != 0ull) k[atomicAdd(&cnt, 1)] = key;
    }
    __syncthreads();
    const int T = cnt;
    if (tid == 0) sortT[c] = T;
    for (int t = tid; t < T; t += BS) {
        unsigned long long key = k[t];
        int pos = 0;
        for (int u = 0; u < T; ++u) pos += (k[u] > key) ? 1 : 0;   // keys unique
        sk[pos] = key;
    }
    __syncthreads();
    for (int j = tid; j < 1024; j += BS) sortedKeys[c * 1024 + j] = sk[j];
}

// ---------------- hist: pos(q) for every pred via binary search ----------
// pos(q) = #{TP keys > key_q}. rank(s) = prefix(hist)[s] - 1 (self removed).
__global__ __launch_bounds__(BS) void hist_kernel(
        const float* __restrict__ scoreC,
        const unsigned long long* __restrict__ sortedKeys,
        int* __restrict__ gHist) {
    __shared__ unsigned long long sK[1024];
    __shared__ int h[1024];
    const int c = blockIdx.y, tid = threadIdx.x;
    for (int j = tid; j < 1024; j += BS) { sK[j] = sortedKeys[c * 1024 + j]; h[j] = 0; }
    __syncthreads();
    const int start = blockIdx.x * CHSZ;
    const int end   = min(start + CHSZ, P);
    const float* sc = scoreC + (size_t)c * P;
    for (int i = start + tid; i < end; i += BS) {
        unsigned long long kq =
            ((unsigned long long)__float_as_uint(sc[i]) << 32) | (unsigned)(P - 1 - i);
        int lo = 0;   // count of sorted-desc keys > kq (pads are 0, never > kq)
        #pragma unroll
        for (int step = 512; step > 0; step >>= 1)
            if (sK[lo + step - 1] > kq) lo += step;
        atomicAdd(&h[lo], 1);   // LDS
    }
    __syncthreads();
    for (int j = tid; j < 1024; j += BS)
        if (h[j]) atomicAdd(&gHist[c * 1024 + j], h[j]);   // no-return
}

// ---------------- ap: prefix over hist + closed-form terms + fused mean -----
// TP at sorted position s has ordinal k = s+1 and sorted rank r = prefix-1.
// precision = k/(r+1) exactly (ctp+cfp == r+1; 1e-9 rounds away in f32);
// term = ((k/800 - (k-1)/800) * (k/(r+1) + (k-1)/r)) * 0.5 — reference op
// order; r == 0 contributes nothing. Last-arriving block computes the mean
// with a deterministic serial in-order sum.
__global__ __launch_bounds__(BS) void ap2_kernel(
        const int* __restrict__ sortT, const int* __restrict__ gHist,
        float* __restrict__ ap, int* __restrict__ doneCnt,
        float* __restrict__ out) {
    __shared__ int ha[1024];
    __shared__ int hb[1024];
    __shared__ float red[BS];
    __shared__ int lastFlag;
    __shared__ float sap[C];
    const int c = blockIdx.x, tid = threadIdx.x;
    const int T = sortT[c];
    for (int j = tid; j < 1024; j += BS) ha[j] = gHist[c * 1024 + j];
    __syncthreads();
    int* src = ha; int* dst = hb;
    for (int o = 1; o < 1024; o <<= 1) {
        for (int j = tid; j < 1024; j += BS)
            dst[j] = src[j] + ((j >= o) ? src[j - o] : 0);
        __syncthreads();
        int* tmp = src; src = dst; dst = tmp;
    }
    float sum = 0.0f;
    for (int s = tid; s < T; s += BS) {
        int r = src[s] - 1;          // inclusive prefix minus self
        if (r >= 1) {
            float kf  = (float)(s + 1);
            float km  = (float)s;
            float ri  = __fdiv_rn(kf, 800.0f);
            float rim = __fdiv_rn(km, 800.0f);
            float pi  = __fdiv_rn(kf, (float)(r + 1));
            float pim = __fdiv_rn(km, (float)r);
            sum = __fadd_rn(sum,
                  __fmul_rn(__fmul_rn(__fsub_rn(ri, rim), __fadd_rn(pi, pim)), 0.5f));
        }
    }
    red[tid] = sum;
    __syncthreads();
    for (int s2 = BS / 2; s2 > 0; s2 >>= 1) {
        if (tid < s2) red[tid] = __fadd_rn(red[tid], red[tid + s2]);
        __syncthreads();
    }
    if (tid == 0) {
        ap[c] = red[0];
        __threadfence();                                  // publish ap[c]
        lastFlag = (atomicAdd(doneCnt, 1) == C - 1);      // device-scope
    }
    __syncthreads();
    if (lastFlag) {
        __threadfence();                                  // acquire all ap[]
        if (tid < C) sap[tid] = ((volatile float*)ap)[tid];
        __syncthreads();
        if (tid == 0) {
            float s = 0.0f;
            for (int cc = 0; cc < C; ++cc) s = __fadd_rn(s, sap[cc]);
            out[0] = __fdiv_rn(s, 80.0f);
        }
    }
}

extern "C" void kernel_launch(void* const* d_in, const int* in_sizes, int n_in,
                              void* d_out, int out_size, void* d_ws, size_t ws_size,
                              hipStream_t stream) {
    const float* pred = (const float*)d_in[0];   // [C, P, 7] f32
    const float* gt   = (const float*)d_in[1];   // [C, G, 7] f32
    float* out = (float*)d_out;

    // Workspace layout. Staged path needs ~56 MB (sBox 38.4 MB); fallback
    // (exact R5 structure) needs ~22 MB. Branch is on ws_size only — constant
    // across calls, graph-capture safe. gt_bin zeroes everything
    // read-before-write (gtKey/predCnt/gHist/doneCnt).
    char* ws = (char*)d_ws;
    int*                doneCnt    = (int*)               (ws + 0);
    int*                sortT      = (int*)               (ws + 512);
    float*              ap         = (float*)             (ws + 1024);
    int*                predCnt    = (int*)               (ws + 2048);     //  20480 B
    int*                predOff    = (int*)               (ws + 22528);
    int*                predCur    = (int*)               (ws + 43008);
    int*                gtCnt      = (int*)               (ws + 63488);
    int*                gtOff      = (int*)               (ws + 83968);
    int*                gtIdx      = (int*)               (ws + 104448);   // 256000 B
    float*              gtAbe      = (float*)             (ws + 360448);   // 256000 B
    unsigned long long* gtKey      = (unsigned long long*)(ws + 616448);   // 512000 B
    unsigned long long* sortedKeys = (unsigned long long*)(ws + 1128448);  // 655360 B
    int*                gHist      = (int*)               (ws + 1783808);  // 327680 B
    float4*             gtBox      = (float4*)            (ws + 2111488);  // 1.024 MB (16-aligned)
    float*              scoreC     = (float*)             (ws + 3135488);  // 9.6 MB
    // staged-only region (overlaps fallback's predP):
    float4*             sBox       = (float4*)            (ws + 12735488); // 38.4 MB (16-aligned)
    unsigned short*     sPid       = (unsigned short*)    (ws + 51135488); // 4.8 MB
    int*                predP      = (int*)               (ws + 12735488); // 9.6 MB (fallback)
    const size_t NEED_STAGED = 55935488;

    const bool staged = (ws_size >= NEED_STAGED);

    gt_bin_kernel<<<C, BS, 0, stream>>>(gt, gtCnt, gtOff, gtBox, gtAbe, gtIdx,
                                        gtKey, predCnt, gHist, doneCnt);
    pred_prep_kernel<<<dim3(P_BLK, C), BS, 0, stream>>>(pred, predCnt, scoreC);
    pred_scan_kernel<<<C, 64, 0, stream>>>(predCnt, predOff, predCur);
    if (staged) {
        pred_scatter_staged_kernel<<<dim3(P_BLK, C), BS, 0, stream>>>(pred, predCur, sBox, sPid);
        match_staged_kernel<<<dim3(NC, C, NCH), BS, 0, stream>>>(
            gtOff, gtCnt, gtBox, gtAbe, gtIdx, predOff, predCnt, sBox, sPid, scoreC, gtKey);
    } else {
        pred_scatter_direct_kernel<<<dim3(P_BLK, C), BS, 0, stream>>>(pred, predCur, predP);
        match_direct_kernel<<<dim3(NC, C, NCH), BS, 0, stream>>>(
            pred, gtOff, gtCnt, gtBox, gtAbe, gtIdx, predOff, predCnt, predP, gtKey);
    }
    sortc_kernel<<<C, BS, 0, stream>>>(gtKey, sortedKeys, sortT);
    hist_kernel<<<dim3(HCH, C), BS, 0, stream>>>(scoreC, sortedKeys, gHist);
    ap2_kernel<<<C, BS, 0, stream>>>(sortT, gHist, ap, doneCnt, out);
}